// Round 7
// baseline (184.296 us; speedup 1.0000x reference)
//
#include <hip/hip_runtime.h>
#include <hip/hip_bf16.h>

#define N_NODES 50000
#define N_EDGES 20000
#define EDGE_K  32
#define CH      256
#define N_INC   (N_EDGES * EDGE_K)   // 640000 incidences
#define ELL_CAP 64                   // max node degree capacity (Poisson(12.8) -> P(>64) ~ 1e-30)

typedef __attribute__((ext_vector_type(4))) float f32x4;
typedef __attribute__((ext_vector_type(8))) short bf16x8;

static __device__ __forceinline__ unsigned short f2bf(float f) {
    __hip_bfloat16 h = __float2bfloat16(f);
    return *reinterpret_cast<unsigned short*>(&h);
}

static __device__ __forceinline__ float bf2f(unsigned short u) {
    unsigned int b = ((unsigned int)u) << 16;
    float f;
    __builtin_memcpy(&f, &b, 4);
    return f;
}

// Fused prep: [0, CB) convert x->bf16 | [CB, CB+256) transpose W->bf16 | rest zero deg
#define CONV_BLOCKS ((N_NODES * CH / 4 + 255) / 256)   // 12500
#define ZERO_BLOCKS ((N_NODES + 255) / 256)            // 196
__global__ void prep_kernel(const float* __restrict__ x, unsigned short* __restrict__ xb,
                            const float* __restrict__ w, unsigned short* __restrict__ wt,
                            int* __restrict__ deg) {
    int b = blockIdx.x;
    if (b < CONV_BLOCKS) {
        int i = b * 256 + threadIdx.x;
        if (i < N_NODES * CH / 4) {
            f32x4 v = reinterpret_cast<const f32x4*>(x)[i];
            ushort4 s;
            s.x = f2bf(v.x);
            s.y = f2bf(v.y);
            s.z = f2bf(v.z);
            s.w = f2bf(v.w);
            reinterpret_cast<ushort4*>(xb)[i] = s;
        }
    } else if (b < CONV_BLOCKS + CH) {
        int n = b - CONV_BLOCKS;   // 0..255
        int k = threadIdx.x;       // 0..255
        wt[n * CH + k] = f2bf(w[k * CH + n]);
    } else {
        int i = (b - CONV_BLOCKS - CH) * 256 + threadIdx.x;
        if (i < N_NODES) deg[i] = 0;
    }
}

// Fused ELL-fill (HEAD of grid, XCD-partitioned) + gather (tail, floods in behind).
//  fill: 2000 blocks = 250 incidence-windows x 8 node-range groups; group = blockIdx%8
//        (matches XCD round-robin) so each deg/ell line is written by ONE XCD.
//  gather: es[e][c] = sum_k xb[he[e][k]][c], 4 edge-waves per block.
#define FILL_GROUPS   8
#define NODES_PER_GRP (N_NODES / FILL_GROUPS)          // 6250
#define FILL_WIN      2560                              // incidences per fill block (10x256)
#define FILL_BLOCKS   ((N_INC / FILL_WIN) * FILL_GROUPS) // 250*8 = 2000
#define GATHER_BLOCKS ((N_EDGES + 3) / 4)               // 5000
__global__ void gather_fill_kernel(const unsigned short* __restrict__ xb,
                                   const int* __restrict__ he,
                                   unsigned short* __restrict__ es,
                                   int* __restrict__ deg,
                                   unsigned short* __restrict__ ell) {
    int b = blockIdx.x;
    if (b < FILL_BLOCKS) {
        int g  = b % FILL_GROUPS;             // == b%8 == XCD (round-robin heuristic)
        int wn = b / FILL_GROUPS;             // incidence window
        int lo = g * NODES_PER_GRP, hi = lo + NODES_PER_GRP;
        int base = wn * FILL_WIN;
#pragma unroll
        for (int it = 0; it < FILL_WIN / 256; ++it) {
            int i = base + it * 256 + threadIdx.x;
            int node = he[i];
            if (node >= lo && node < hi) {
                int slot = atomicAdd(&deg[node], 1);
                if (slot < ELL_CAP)
                    ell[(size_t)node * ELL_CAP + slot] = (unsigned short)(i >> 5);
            }
        }
    } else {
        int wave = (b - FILL_BLOCKS) * 4 + (threadIdx.x >> 6);
        int lane = threadIdx.x & 63;
        if (wave >= N_EDGES) return;
        int myidx = he[wave * EDGE_K + (lane & 31)];   // wave's whole index list in regs
        const ushort4* xb4 = reinterpret_cast<const ushort4*>(xb);
        f32x4 acc = {0.f, 0.f, 0.f, 0.f};
#pragma unroll
        for (int k = 0; k < EDGE_K; ++k) {
            int e = __shfl(myidx, k, 64);              // VALU dep only — loads pipeline
            ushort4 v = xb4[(size_t)e * (CH / 4) + lane];
            acc.x += bf2f(v.x);
            acc.y += bf2f(v.y);
            acc.z += bf2f(v.z);
            acc.w += bf2f(v.w);
        }
        ushort4 s;
        s.x = f2bf(acc.x);
        s.y = f2bf(acc.y);
        s.z = f2bf(acc.z);
        s.w = f2bf(acc.w);
        reinterpret_cast<ushort4*>(es + (size_t)wave * CH)[lane] = s;
    }
}

// Fused apply + GEMM + ReLU:
//   z[n][:] = sum_{j<deg[n]} es[ell[n][j]][:]      (phase 1, LDS staging, bf16)
//   out[n][:] = relu(z[n][:] @ W)                  (phase 2, MFMA, W from L2)
// Block = 32 nodes, 4 waves. Phase 1: wave w gathers nodes w*8..w*8+7.
// Phase 2: wave w computes rows (w>>1)*16..+16, cols (w&1)*128..+128.
#define AP_NODES 32
#define ZPAD     264   // row stride in ushorts: 528 B, 16B-aligned, banks spread
__global__ __launch_bounds__(256) void apply_gemm_kernel(const unsigned short* __restrict__ es,
                                                         const unsigned short* __restrict__ wt,
                                                         const int* __restrict__ deg,
                                                         const unsigned short* __restrict__ ell,
                                                         float* __restrict__ out) {
    __shared__ unsigned short zs[AP_NODES * ZPAD];   // 16896 B
    int w    = threadIdx.x >> 6;
    int lane = threadIdx.x & 63;
    int nbase = blockIdx.x * AP_NODES;

    // ---- phase 1: gather z rows into LDS ----
    const ushort4* es4 = reinterpret_cast<const ushort4*>(es);
    for (int t = 0; t < 8; ++t) {
        int local = w * 8 + t;
        int node  = nbase + local;
        int nr    = node < N_NODES ? node : N_NODES - 1;
        int d     = node < N_NODES ? deg[nr] : 0;
        if (d > ELL_CAP) d = ELL_CAP;
        int myidx = (int)ell[(size_t)nr * ELL_CAP + lane];  // whole ELL row in regs
        f32x4 acc = {0.f, 0.f, 0.f, 0.f};
        int j = 0;
        for (; j + 4 <= d; j += 4) {
            int e0 = __shfl(myidx, j + 0, 64);
            int e1 = __shfl(myidx, j + 1, 64);
            int e2 = __shfl(myidx, j + 2, 64);
            int e3 = __shfl(myidx, j + 3, 64);
            ushort4 v0 = es4[(size_t)e0 * (CH / 4) + lane];
            ushort4 v1 = es4[(size_t)e1 * (CH / 4) + lane];
            ushort4 v2 = es4[(size_t)e2 * (CH / 4) + lane];
            ushort4 v3 = es4[(size_t)e3 * (CH / 4) + lane];
            acc.x += bf2f(v0.x) + bf2f(v1.x) + bf2f(v2.x) + bf2f(v3.x);
            acc.y += bf2f(v0.y) + bf2f(v1.y) + bf2f(v2.y) + bf2f(v3.y);
            acc.z += bf2f(v0.z) + bf2f(v1.z) + bf2f(v2.z) + bf2f(v3.z);
            acc.w += bf2f(v0.w) + bf2f(v1.w) + bf2f(v2.w) + bf2f(v3.w);
        }
        for (; j < d; ++j) {
            int e = __shfl(myidx, j, 64);
            ushort4 v = es4[(size_t)e * (CH / 4) + lane];
            acc.x += bf2f(v.x);
            acc.y += bf2f(v.y);
            acc.z += bf2f(v.z);
            acc.w += bf2f(v.w);
        }
        ushort4 s;
        s.x = f2bf(acc.x);
        s.y = f2bf(acc.y);
        s.z = f2bf(acc.z);
        s.w = f2bf(acc.w);
        *reinterpret_cast<ushort4*>(&zs[local * ZPAD + lane * 4]) = s;
    }
    __syncthreads();

    // ---- phase 2: MFMA z @ W, relu, store ----
    int strip = w >> 1;          // row strip: 16 rows at strip*16
    int half  = w & 1;           // col half: n-tiles [half*8, half*8+8)
    int lr = lane & 15;
    int lg = lane >> 4;

    f32x4 acc[8] = {};
    const unsigned short* zrow = &zs[(strip * 16 + lr) * ZPAD + lg * 8];
#pragma unroll
    for (int kk = 0; kk < CH; kk += 32) {
        bf16x8 a = *reinterpret_cast<const bf16x8*>(zrow + kk);
#pragma unroll
        for (int nt = 0; nt < 8; ++nt) {
            bf16x8 bb = *reinterpret_cast<const bf16x8*>(
                wt + (size_t)((half * 8 + nt) * 16 + lr) * CH + kk + lg * 8);
            acc[nt] = __builtin_amdgcn_mfma_f32_16x16x32_bf16(a, bb, acc[nt], 0, 0, 0);
        }
    }

    // D layout: col = lane&15, row = (lane>>4)*4 + r   [measured m89]
#pragma unroll
    for (int nt = 0; nt < 8; ++nt) {
#pragma unroll
        for (int r = 0; r < 4; ++r) {
            int node = nbase + strip * 16 + lg * 4 + r;
            if (node < N_NODES) {
                float v = acc[nt][r];
                out[(size_t)node * CH + (half * 8 + nt) * 16 + lr] = fmaxf(v, 0.f);
            }
        }
    }
}

extern "C" void kernel_launch(void* const* d_in, const int* in_sizes, int n_in,
                              void* d_out, int out_size, void* d_ws, size_t ws_size,
                              hipStream_t stream) {
    const float* x  = (const float*)d_in[0];
    const int*   he = (const int*)d_in[1];
    const float* w  = (const float*)d_in[2];
    float* out = (float*)d_out;

    // workspace layout
    char* ws = (char*)d_ws;
    unsigned short* wt  = (unsigned short*)ws;                       // 131072 B
    unsigned short* es  = (unsigned short*)(ws + 131072);            // 10240000 B
    int* deg = (int*)(ws + 131072 + 10240000);                       // 200000 B
    unsigned short* ell = (unsigned short*)(ws + 131072 + 10240000 + 200000); // 6400000 B

    // xb (bf16 x, 25.6 MB) lives inside d_out (51.2 MB f32): d_out is only
    // written by the final apply_gemm_kernel, so lifetimes are disjoint.
    unsigned short* xb = (unsigned short*)d_out;

    prep_kernel<<<CONV_BLOCKS + CH + ZERO_BLOCKS, 256, 0, stream>>>(x, xb, w, wt, deg);

    gather_fill_kernel<<<FILL_BLOCKS + GATHER_BLOCKS, 256, 0, stream>>>(xb, he, es, deg, ell);

    {   // 32 nodes per block
        int blocks = (N_NODES + AP_NODES - 1) / AP_NODES;
        apply_gemm_kernel<<<blocks, 256, 0, stream>>>(es, wt, deg, ell, out);
    }
}

// Round 8
// 158.492 us; speedup vs baseline: 1.1628x; 1.1628x over previous
//
#include <hip/hip_runtime.h>
#include <hip/hip_bf16.h>

#define N_NODES 50000
#define N_EDGES 20000
#define EDGE_K  32
#define CH      256
#define N_INC   (N_EDGES * EDGE_K)   // 640000 incidences
#define ELL_CAP 64                   // max node degree capacity (Poisson(12.8) -> P(>64) ~ 1e-30)

typedef __attribute__((ext_vector_type(4))) float f32x4;
typedef __attribute__((ext_vector_type(8))) short bf16x8;

static __device__ __forceinline__ unsigned short f2bf(float f) {
    __hip_bfloat16 h = __float2bfloat16(f);
    return *reinterpret_cast<unsigned short*>(&h);
}

static __device__ __forceinline__ float bf2f(unsigned short u) {
    unsigned int b = ((unsigned int)u) << 16;
    float f;
    __builtin_memcpy(&f, &b, 4);
    return f;
}

// Fused prep: [0, CB) convert x->bf16 | [CB, CB+256) transpose W->bf16 | rest zero deg
#define CONV_BLOCKS ((N_NODES * CH / 4 + 255) / 256)   // 12500
#define ZERO_BLOCKS ((N_NODES + 255) / 256)            // 196
__global__ void prep_kernel(const float* __restrict__ x, unsigned short* __restrict__ xb,
                            const float* __restrict__ w, unsigned short* __restrict__ wt,
                            int* __restrict__ deg) {
    int b = blockIdx.x;
    if (b < CONV_BLOCKS) {
        int i = b * 256 + threadIdx.x;
        if (i < N_NODES * CH / 4) {
            f32x4 v = reinterpret_cast<const f32x4*>(x)[i];
            ushort4 s;
            s.x = f2bf(v.x);
            s.y = f2bf(v.y);
            s.z = f2bf(v.z);
            s.w = f2bf(v.w);
            reinterpret_cast<ushort4*>(xb)[i] = s;
        }
    } else if (b < CONV_BLOCKS + CH) {
        int n = b - CONV_BLOCKS;   // 0..255
        int k = threadIdx.x;       // 0..255
        wt[n * CH + k] = f2bf(w[k * CH + n]);
    } else {
        int i = (b - CONV_BLOCKS - CH) * 256 + threadIdx.x;
        if (i < N_NODES) deg[i] = 0;
    }
}

// Fused ELL-fill (HEAD of grid, XCD-partitioned) + gather (tail, floods in behind).
//  fill: 2000 blocks = 250 incidence-windows x 8 node-range groups; group = blockIdx%8
//        (matches XCD round-robin) so each deg/ell line is written by ONE XCD.
//  gather: es[e][c] = sum_k xb[he[e][k]][c], 4 edge-waves per block.
#define FILL_GROUPS   8
#define NODES_PER_GRP (N_NODES / FILL_GROUPS)          // 6250
#define FILL_WIN      2560                              // incidences per fill block (10x256)
#define FILL_BLOCKS   ((N_INC / FILL_WIN) * FILL_GROUPS) // 250*8 = 2000
#define GATHER_BLOCKS ((N_EDGES + 3) / 4)               // 5000
__global__ void gather_fill_kernel(const unsigned short* __restrict__ xb,
                                   const int* __restrict__ he,
                                   unsigned short* __restrict__ es,
                                   int* __restrict__ deg,
                                   unsigned short* __restrict__ ell) {
    int b = blockIdx.x;
    if (b < FILL_BLOCKS) {
        int g  = b % FILL_GROUPS;             // == b%8 == XCD (round-robin heuristic)
        int wn = b / FILL_GROUPS;             // incidence window
        int lo = g * NODES_PER_GRP, hi = lo + NODES_PER_GRP;
        int base = wn * FILL_WIN;
#pragma unroll
        for (int it = 0; it < FILL_WIN / 256; ++it) {
            int i = base + it * 256 + threadIdx.x;
            int node = he[i];
            if (node >= lo && node < hi) {
                int slot = atomicAdd(&deg[node], 1);
                if (slot < ELL_CAP)
                    ell[(size_t)node * ELL_CAP + slot] = (unsigned short)(i >> 5);
            }
        }
    } else {
        int wave = (b - FILL_BLOCKS) * 4 + (threadIdx.x >> 6);
        int lane = threadIdx.x & 63;
        if (wave >= N_EDGES) return;
        int myidx = he[wave * EDGE_K + (lane & 31)];   // wave's whole index list in regs
        const ushort4* xb4 = reinterpret_cast<const ushort4*>(xb);
        f32x4 acc = {0.f, 0.f, 0.f, 0.f};
#pragma unroll
        for (int k = 0; k < EDGE_K; ++k) {
            int e = __shfl(myidx, k, 64);              // VALU dep only — loads pipeline
            ushort4 v = xb4[(size_t)e * (CH / 4) + lane];
            acc.x += bf2f(v.x);
            acc.y += bf2f(v.y);
            acc.z += bf2f(v.z);
            acc.w += bf2f(v.w);
        }
        ushort4 s;
        s.x = f2bf(acc.x);
        s.y = f2bf(acc.y);
        s.z = f2bf(acc.z);
        s.w = f2bf(acc.w);
        reinterpret_cast<ushort4*>(es + (size_t)wave * CH)[lane] = s;
    }
}

// Y[20000][256] bf16 = es(bf16) @ W(bf16)   via mfma_f32_16x16x32_bf16
__global__ __launch_bounds__(256) void gemm_kernel(const unsigned short* __restrict__ es,
                                                   const unsigned short* __restrict__ wt,
                                                   unsigned short* __restrict__ yb) {
    int wid  = threadIdx.x >> 6;
    int lane = threadIdx.x & 63;
    int m0   = blockIdx.x * 64 + wid * 16;
    if (m0 >= N_EDGES) return;
    int lr = lane & 15;   // row-lane (A) / col-lane (B, D)
    int lg = lane >> 4;   // k-group

    f32x4 acc[16] = {};   // 16 n-tiles of 16 cols

    const unsigned short* arow = es + (size_t)(m0 + lr) * CH + lg * 8;
#pragma unroll
    for (int kk = 0; kk < CH; kk += 32) {
        bf16x8 a = *reinterpret_cast<const bf16x8*>(arow + kk);
#pragma unroll
        for (int nt = 0; nt < 16; ++nt) {
            bf16x8 b = *reinterpret_cast<const bf16x8*>(
                wt + (size_t)(nt * 16 + lr) * CH + kk + lg * 8);
            acc[nt] = __builtin_amdgcn_mfma_f32_16x16x32_bf16(a, b, acc[nt], 0, 0, 0);
        }
    }

    // D layout: col = lane&15, row = (lane>>4)*4 + r   [measured m89]
#pragma unroll
    for (int nt = 0; nt < 16; ++nt) {
#pragma unroll
        for (int r = 0; r < 4; ++r) {
            yb[(size_t)(m0 + lg * 4 + r) * CH + nt * 16 + lr] = f2bf(acc[nt][r]);
        }
    }
}

// out[n][:] = relu( sum_{j < deg[n]} yb[ell[n][j]][:] )
// one wave per node; ELL row preloaded to registers (one ushort load/lane),
// shfl-broadcast, 4x-unrolled independent data loads for MLP.
__global__ void apply_kernel(const unsigned short* __restrict__ yb, const int* __restrict__ deg,
                             const unsigned short* __restrict__ ell, float* __restrict__ out) {
    int node = (int)((blockIdx.x * blockDim.x + threadIdx.x) >> 6);
    int lane = threadIdx.x & 63;
    if (node >= N_NODES) return;
    int d = deg[node];
    if (d > ELL_CAP) d = ELL_CAP;
    int myidx = (int)ell[(size_t)node * ELL_CAP + lane];  // whole ELL row in wave registers
    const ushort4* yb4 = reinterpret_cast<const ushort4*>(yb);
    f32x4 acc = {0.f, 0.f, 0.f, 0.f};
    int j = 0;
    for (; j + 4 <= d; j += 4) {
        int e0 = __shfl(myidx, j + 0, 64);
        int e1 = __shfl(myidx, j + 1, 64);
        int e2 = __shfl(myidx, j + 2, 64);
        int e3 = __shfl(myidx, j + 3, 64);
        ushort4 v0 = yb4[(size_t)e0 * (CH / 4) + lane];
        ushort4 v1 = yb4[(size_t)e1 * (CH / 4) + lane];
        ushort4 v2 = yb4[(size_t)e2 * (CH / 4) + lane];
        ushort4 v3 = yb4[(size_t)e3 * (CH / 4) + lane];
        acc.x += bf2f(v0.x) + bf2f(v1.x) + bf2f(v2.x) + bf2f(v3.x);
        acc.y += bf2f(v0.y) + bf2f(v1.y) + bf2f(v2.y) + bf2f(v3.y);
        acc.z += bf2f(v0.z) + bf2f(v1.z) + bf2f(v2.z) + bf2f(v3.z);
        acc.w += bf2f(v0.w) + bf2f(v1.w) + bf2f(v2.w) + bf2f(v3.w);
    }
    for (; j < d; ++j) {
        int e = __shfl(myidx, j, 64);
        ushort4 v = yb4[(size_t)e * (CH / 4) + lane];
        acc.x += bf2f(v.x);
        acc.y += bf2f(v.y);
        acc.z += bf2f(v.z);
        acc.w += bf2f(v.w);
    }
    acc.x = fmaxf(acc.x, 0.f);
    acc.y = fmaxf(acc.y, 0.f);
    acc.z = fmaxf(acc.z, 0.f);
    acc.w = fmaxf(acc.w, 0.f);
    reinterpret_cast<f32x4*>(out + (size_t)node * CH)[lane] = acc;
}

extern "C" void kernel_launch(void* const* d_in, const int* in_sizes, int n_in,
                              void* d_out, int out_size, void* d_ws, size_t ws_size,
                              hipStream_t stream) {
    const float* x  = (const float*)d_in[0];
    const int*   he = (const int*)d_in[1];
    const float* w  = (const float*)d_in[2];
    float* out = (float*)d_out;

    // workspace layout
    char* ws = (char*)d_ws;
    unsigned short* wt  = (unsigned short*)ws;                       // 131072 B
    unsigned short* es  = (unsigned short*)(ws + 131072);            // 10240000 B
    unsigned short* yb  = (unsigned short*)(ws + 131072 + 10240000); // 10240000 B
    int* deg = (int*)(ws + 131072 + 10240000 + 10240000);            // 200000 B
    unsigned short* ell = (unsigned short*)(ws + 131072 + 10240000 + 10240000 + 200000); // 6400000 B

    // xb (bf16 x, 25.6 MB) lives inside d_out (51.2 MB f32): d_out is only
    // written by the final apply_kernel, so lifetimes are disjoint.
    unsigned short* xb = (unsigned short*)d_out;

    prep_kernel<<<CONV_BLOCKS + CH + ZERO_BLOCKS, 256, 0, stream>>>(x, xb, w, wt, deg);

    gather_fill_kernel<<<FILL_BLOCKS + GATHER_BLOCKS, 256, 0, stream>>>(xb, he, es, deg, ell);

    {
        int blocks = (N_EDGES + 63) / 64;
        gemm_kernel<<<blocks, 256, 0, stream>>>(es, wt, yb);
    }

    {   // 4 nodes (waves) per 256-thread block
        int blocks = (N_NODES + 3) / 4;
        apply_kernel<<<blocks, 256, 0, stream>>>(yb, deg, ell, out);
    }
}

// Round 9
// 146.659 us; speedup vs baseline: 1.2566x; 1.0807x over previous
//
#include <hip/hip_runtime.h>
#include <hip/hip_bf16.h>

#define N_NODES 50000
#define N_EDGES 20000
#define EDGE_K  32
#define CH      256
#define N_INC   (N_EDGES * EDGE_K)   // 640000 incidences
#define ELL_CAP 64                   // max node degree capacity (Poisson(12.8) -> P(>64) ~ 1e-30)

typedef __attribute__((ext_vector_type(4))) float f32x4;
typedef __attribute__((ext_vector_type(8))) short bf16x8;

static __device__ __forceinline__ unsigned short f2bf(float f) {
    __hip_bfloat16 h = __float2bfloat16(f);
    return *reinterpret_cast<unsigned short*>(&h);
}

static __device__ __forceinline__ float bf2f(unsigned short u) {
    unsigned int b = ((unsigned int)u) << 16;
    float f;
    __builtin_memcpy(&f, &b, 4);
    return f;
}

// Fused prep: [0, CB) convert x->bf16 | [CB, CB+256) transpose W->bf16 | rest zero deg
#define CONV_BLOCKS ((N_NODES * CH / 4 + 255) / 256)   // 12500
#define ZERO_BLOCKS ((N_NODES + 255) / 256)            // 196
__global__ void prep_kernel(const float* __restrict__ x, unsigned short* __restrict__ xb,
                            const float* __restrict__ w, unsigned short* __restrict__ wt,
                            int* __restrict__ deg) {
    int b = blockIdx.x;
    if (b < CONV_BLOCKS) {
        int i = b * 256 + threadIdx.x;
        if (i < N_NODES * CH / 4) {
            f32x4 v = reinterpret_cast<const f32x4*>(x)[i];
            ushort4 s;
            s.x = f2bf(v.x);
            s.y = f2bf(v.y);
            s.z = f2bf(v.z);
            s.w = f2bf(v.w);
            reinterpret_cast<ushort4*>(xb)[i] = s;
        }
    } else if (b < CONV_BLOCKS + CH) {
        int n = b - CONV_BLOCKS;   // 0..255
        int k = threadIdx.x;       // 0..255
        wt[n * CH + k] = f2bf(w[k * CH + n]);
    } else {
        int i = (b - CONV_BLOCKS - CH) * 256 + threadIdx.x;
        if (i < N_NODES) deg[i] = 0;
    }
}

// Fused: ELL-fill (HEAD, XCD-partitioned) + gather-and-GEMM (tail).
//  fill: 2000 blocks = 250 incidence-windows x 8 node-range groups (group=blockIdx%8
//        matches XCD round-robin -> each deg/ell line written by ONE XCD).
//  gather+gemm: block owns 16 edges. Phase 1: wave w gathers 4 edges into LDS
//        (uniform work: 4x32 independent loads -> no R6-style imbalance).
//        Phase 2: MFMA those 16 rows x W (wave w owns 64 cols), write yb bf16.
#define FILL_GROUPS   8
#define NODES_PER_GRP (N_NODES / FILL_GROUPS)          // 6250
#define FILL_WIN      2560                              // incidences per fill block
#define FILL_BLOCKS   ((N_INC / FILL_WIN) * FILL_GROUPS) // 250*8 = 2000
#define GG_BLOCKS     (N_EDGES / 16)                    // 1250
#define ZPAD          264   // LDS row stride in ushorts (528 B, 16B-aligned)
__global__ __launch_bounds__(256) void gather_fill_gemm_kernel(
        const unsigned short* __restrict__ xb, const int* __restrict__ he,
        const unsigned short* __restrict__ wt, unsigned short* __restrict__ yb,
        int* __restrict__ deg, unsigned short* __restrict__ ell) {
    int b = blockIdx.x;
    if (b < FILL_BLOCKS) {
        int g  = b % FILL_GROUPS;             // == XCD (round-robin heuristic)
        int wn = b / FILL_GROUPS;             // incidence window
        int lo = g * NODES_PER_GRP, hi = lo + NODES_PER_GRP;
        int base = wn * FILL_WIN;
#pragma unroll
        for (int it = 0; it < FILL_WIN / 256; ++it) {
            int i = base + it * 256 + threadIdx.x;
            int node = he[i];
            if (node >= lo && node < hi) {
                int slot = atomicAdd(&deg[node], 1);
                if (slot < ELL_CAP)
                    ell[(size_t)node * ELL_CAP + slot] = (unsigned short)(i >> 5);
            }
        }
        return;
    }

    __shared__ unsigned short zs[16 * ZPAD];   // 8448 B
    int w    = threadIdx.x >> 6;
    int lane = threadIdx.x & 63;
    int ebase = (b - FILL_BLOCKS) * 16;

    // ---- phase 1: wave w gathers edges ebase+w*4 .. +3 into LDS rows w*4.. ----
    const ushort4* xb4 = reinterpret_cast<const ushort4*>(xb);
    for (int t = 0; t < 4; ++t) {
        int e = ebase + w * 4 + t;
        int myidx = he[e * EDGE_K + (lane & 31)];   // wave's index list in regs
        f32x4 acc = {0.f, 0.f, 0.f, 0.f};
#pragma unroll
        for (int k = 0; k < EDGE_K; ++k) {
            int idx = __shfl(myidx, k, 64);         // VALU dep only — loads pipeline
            ushort4 v = xb4[(size_t)idx * (CH / 4) + lane];
            acc.x += bf2f(v.x);
            acc.y += bf2f(v.y);
            acc.z += bf2f(v.z);
            acc.w += bf2f(v.w);
        }
        ushort4 s;
        s.x = f2bf(acc.x);
        s.y = f2bf(acc.y);
        s.z = f2bf(acc.z);
        s.w = f2bf(acc.w);
        *reinterpret_cast<ushort4*>(&zs[(w * 4 + t) * ZPAD + lane * 4]) = s;
    }
    __syncthreads();

    // ---- phase 2: yb[ebase..+16][:] = zs @ W ; wave w owns cols [w*64, w*64+64) ----
    int lr = lane & 15;
    int lg = lane >> 4;
    f32x4 acc[4] = {};
#pragma unroll
    for (int kk = 0; kk < CH; kk += 32) {
        bf16x8 a = *reinterpret_cast<const bf16x8*>(&zs[lr * ZPAD + kk + lg * 8]);
#pragma unroll
        for (int nt = 0; nt < 4; ++nt) {
            bf16x8 bb = *reinterpret_cast<const bf16x8*>(
                wt + (size_t)((w * 4 + nt) * 16 + lr) * CH + kk + lg * 8);
            acc[nt] = __builtin_amdgcn_mfma_f32_16x16x32_bf16(a, bb, acc[nt], 0, 0, 0);
        }
    }
    // D layout: col = lane&15, row = (lane>>4)*4 + r   [measured m89]
#pragma unroll
    for (int nt = 0; nt < 4; ++nt) {
#pragma unroll
        for (int r = 0; r < 4; ++r) {
            yb[(size_t)(ebase + lg * 4 + r) * CH + (w * 4 + nt) * 16 + lr] = f2bf(acc[nt][r]);
        }
    }
}

// out[n][:] = relu( sum_{j < deg[n]} yb[ell[n][j]][:] )
// one wave per node; ELL row preloaded to registers, shfl-broadcast,
// 8x-unrolled independent data loads for MLP.
__global__ void apply_kernel(const unsigned short* __restrict__ yb, const int* __restrict__ deg,
                             const unsigned short* __restrict__ ell, float* __restrict__ out) {
    int node = (int)((blockIdx.x * blockDim.x + threadIdx.x) >> 6);
    int lane = threadIdx.x & 63;
    if (node >= N_NODES) return;
    int d = deg[node];
    if (d > ELL_CAP) d = ELL_CAP;
    int myidx = (int)ell[(size_t)node * ELL_CAP + lane];  // whole ELL row in wave registers
    const ushort4* yb4 = reinterpret_cast<const ushort4*>(yb);
    f32x4 acc = {0.f, 0.f, 0.f, 0.f};
    int j = 0;
    for (; j + 8 <= d; j += 8) {
        ushort4 v0 = yb4[(size_t)__shfl(myidx, j + 0, 64) * (CH / 4) + lane];
        ushort4 v1 = yb4[(size_t)__shfl(myidx, j + 1, 64) * (CH / 4) + lane];
        ushort4 v2 = yb4[(size_t)__shfl(myidx, j + 2, 64) * (CH / 4) + lane];
        ushort4 v3 = yb4[(size_t)__shfl(myidx, j + 3, 64) * (CH / 4) + lane];
        ushort4 v4 = yb4[(size_t)__shfl(myidx, j + 4, 64) * (CH / 4) + lane];
        ushort4 v5 = yb4[(size_t)__shfl(myidx, j + 5, 64) * (CH / 4) + lane];
        ushort4 v6 = yb4[(size_t)__shfl(myidx, j + 6, 64) * (CH / 4) + lane];
        ushort4 v7 = yb4[(size_t)__shfl(myidx, j + 7, 64) * (CH / 4) + lane];
        acc.x += bf2f(v0.x) + bf2f(v1.x) + bf2f(v2.x) + bf2f(v3.x)
               + bf2f(v4.x) + bf2f(v5.x) + bf2f(v6.x) + bf2f(v7.x);
        acc.y += bf2f(v0.y) + bf2f(v1.y) + bf2f(v2.y) + bf2f(v3.y)
               + bf2f(v4.y) + bf2f(v5.y) + bf2f(v6.y) + bf2f(v7.y);
        acc.z += bf2f(v0.z) + bf2f(v1.z) + bf2f(v2.z) + bf2f(v3.z)
               + bf2f(v4.z) + bf2f(v5.z) + bf2f(v6.z) + bf2f(v7.z);
        acc.w += bf2f(v0.w) + bf2f(v1.w) + bf2f(v2.w) + bf2f(v3.w)
               + bf2f(v4.w) + bf2f(v5.w) + bf2f(v6.w) + bf2f(v7.w);
    }
    for (; j + 4 <= d; j += 4) {
        ushort4 v0 = yb4[(size_t)__shfl(myidx, j + 0, 64) * (CH / 4) + lane];
        ushort4 v1 = yb4[(size_t)__shfl(myidx, j + 1, 64) * (CH / 4) + lane];
        ushort4 v2 = yb4[(size_t)__shfl(myidx, j + 2, 64) * (CH / 4) + lane];
        ushort4 v3 = yb4[(size_t)__shfl(myidx, j + 3, 64) * (CH / 4) + lane];
        acc.x += bf2f(v0.x) + bf2f(v1.x) + bf2f(v2.x) + bf2f(v3.x);
        acc.y += bf2f(v0.y) + bf2f(v1.y) + bf2f(v2.y) + bf2f(v3.y);
        acc.z += bf2f(v0.z) + bf2f(v1.z) + bf2f(v2.z) + bf2f(v3.z);
        acc.w += bf2f(v0.w) + bf2f(v1.w) + bf2f(v2.w) + bf2f(v3.w);
    }
    for (; j < d; ++j) {
        ushort4 v = yb4[(size_t)__shfl(myidx, j, 64) * (CH / 4) + lane];
        acc.x += bf2f(v.x);
        acc.y += bf2f(v.y);
        acc.z += bf2f(v.z);
        acc.w += bf2f(v.w);
    }
    acc.x = fmaxf(acc.x, 0.f);
    acc.y = fmaxf(acc.y, 0.f);
    acc.z = fmaxf(acc.z, 0.f);
    acc.w = fmaxf(acc.w, 0.f);
    reinterpret_cast<f32x4*>(out + (size_t)node * CH)[lane] = acc;
}

extern "C" void kernel_launch(void* const* d_in, const int* in_sizes, int n_in,
                              void* d_out, int out_size, void* d_ws, size_t ws_size,
                              hipStream_t stream) {
    const float* x  = (const float*)d_in[0];
    const int*   he = (const int*)d_in[1];
    const float* w  = (const float*)d_in[2];
    float* out = (float*)d_out;

    // workspace layout (es buffer eliminated by the gather+gemm fusion)
    char* ws = (char*)d_ws;
    unsigned short* wt  = (unsigned short*)ws;                       // 131072 B
    unsigned short* yb  = (unsigned short*)(ws + 131072);            // 10240000 B
    int* deg = (int*)(ws + 131072 + 10240000);                       // 200000 B
    unsigned short* ell = (unsigned short*)(ws + 131072 + 10240000 + 200000); // 6400000 B

    // xb (bf16 x, 25.6 MB) lives inside d_out (51.2 MB f32): d_out is only
    // written by the final apply_kernel, so lifetimes are disjoint.
    unsigned short* xb = (unsigned short*)d_out;

    prep_kernel<<<CONV_BLOCKS + CH + ZERO_BLOCKS, 256, 0, stream>>>(x, xb, w, wt, deg);

    gather_fill_gemm_kernel<<<FILL_BLOCKS + GG_BLOCKS, 256, 0, stream>>>(
        xb, he, wt, yb, deg, ell);

    {   // 4 nodes (waves) per 256-thread block
        int blocks = (N_NODES + 3) / 4;
        apply_kernel<<<blocks, 256, 0, stream>>>(yb, deg, ell, out);
    }
}

// Round 10
// 145.370 us; speedup vs baseline: 1.2678x; 1.0089x over previous
//
#include <hip/hip_runtime.h>
#include <hip/hip_bf16.h>

#define N_NODES 50000
#define N_EDGES 20000
#define EDGE_K  32
#define CH      256
#define N_INC   (N_EDGES * EDGE_K)   // 640000 incidences
#define ELL_CAP 64                   // max node degree capacity (Poisson(12.8))
#define NSLICE  8                    // channel slices == XCD count
#define SCH     32                   // channels per slice (32 x 2B = 64B rows)

typedef __attribute__((ext_vector_type(4))) float f32x4;
typedef __attribute__((ext_vector_type(8))) short bf16x8;

static __device__ __forceinline__ unsigned short f2bf(float f) {
    __hip_bfloat16 h = __float2bfloat16(f);
    return *reinterpret_cast<unsigned short*>(&h);
}
static __device__ __forceinline__ float bflo(unsigned int u) {
    unsigned int b = u << 16;
    float f; __builtin_memcpy(&f, &b, 4); return f;
}
static __device__ __forceinline__ float bfhi(unsigned int u) {
    unsigned int b = u & 0xffff0000u;
    float f; __builtin_memcpy(&f, &b, 4); return f;
}
static __device__ __forceinline__ unsigned int pk2(float a, float b) {
    return (unsigned int)f2bf(a) | ((unsigned int)f2bf(b) << 16);
}

// Fused prep: [0,CB) x->bf16 SLICED [8][N][32] | [CB,CB+256) W^T bf16 | rest zero deg
#define CONV_BLOCKS (N_NODES * CH / 8 / 256)   // 6250
#define ZERO_BLOCKS ((N_NODES + 255) / 256)    // 196
__global__ void prep_kernel(const float* __restrict__ x, unsigned short* __restrict__ xb,
                            const float* __restrict__ w, unsigned short* __restrict__ wt,
                            int* __restrict__ deg) {
    int b = blockIdx.x;
    if (b < CONV_BLOCKS) {
        int i = b * 256 + threadIdx.x;        // one per 8 channels
        int n = i >> 5, sub = i & 31;
        int g = sub >> 2, cp = (sub & 3) * 8;
        const float* src = x + (size_t)n * CH + sub * 8;
        f32x4 v0 = *reinterpret_cast<const f32x4*>(src);
        f32x4 v1 = *reinterpret_cast<const f32x4*>(src + 4);
        uint4 u;
        u.x = pk2(v0.x, v0.y);
        u.y = pk2(v0.z, v0.w);
        u.z = pk2(v1.x, v1.y);
        u.w = pk2(v1.z, v1.w);
        *reinterpret_cast<uint4*>(xb + ((size_t)g * N_NODES + n) * SCH + cp) = u;
    } else if (b < CONV_BLOCKS + CH) {
        int n = b - CONV_BLOCKS;
        int k = threadIdx.x;
        wt[n * CH + k] = f2bf(w[k * CH + n]);
    } else {
        int i = (b - CONV_BLOCKS - CH) * 256 + threadIdx.x;
        if (i < N_NODES) deg[i] = 0;
    }
}

// Fused: ELL-fill (head, XCD-partitioned by node range) + sliced gather (tail,
// slice g = blockIdx%8 pinned to XCD g; each XCD reads ONLY its 3.2MB xb slice
// -> L2-resident). Wave = 4 edges x slice: lanes (ep=l>>4, k=(l>>2)&3, q=l&3),
// 8 rounds of 16B loads, shfl_xor reduce over k.
#define FILL_GROUPS   8
#define NODES_PER_GRP (N_NODES / FILL_GROUPS)
#define FILL_WIN      2560
#define FILL_BLOCKS   ((N_INC / FILL_WIN) * FILL_GROUPS) // 2000 (multiple of 8)
#define GGRP          (N_EDGES / 16)                     // 1250
#define GATHER_BLOCKS (GGRP * NSLICE)                    // 10000
__global__ __launch_bounds__(256) void gather_fill_kernel(
        const unsigned short* __restrict__ xb, const int* __restrict__ he,
        unsigned short* __restrict__ es, int* __restrict__ deg,
        unsigned short* __restrict__ ell) {
    int b = blockIdx.x;
    if (b < FILL_BLOCKS) {
        int g  = b % FILL_GROUPS;
        int wn = b / FILL_GROUPS;
        int lo = g * NODES_PER_GRP, hi = lo + NODES_PER_GRP;
        int base = wn * FILL_WIN;
#pragma unroll
        for (int it = 0; it < FILL_WIN / 256; ++it) {
            int i = base + it * 256 + threadIdx.x;
            int node = he[i];
            if (node >= lo && node < hi) {
                int slot = atomicAdd(&deg[node], 1);
                if (slot < ELL_CAP)
                    ell[(size_t)node * ELL_CAP + slot] = (unsigned short)(i >> 5);
            }
        }
        return;
    }
    int gb  = b - FILL_BLOCKS;
    int g   = gb & 7;                 // slice == XCD (round-robin heuristic)
    int grp = gb >> 3;
    int w = threadIdx.x >> 6, lane = threadIdx.x & 63;
    int ebase = grp * 16 + w * 4;     // this wave's 4 edges
    const int* hp = he + (size_t)ebase * EDGE_K;
    int s = lane & 15;
    int ep = lane >> 4, k = (lane >> 2) & 3, q = lane & 3;
    int mA = hp[ep * 32 + s];         // edge ep, node slots 0..15
    int mB = hp[ep * 32 + 16 + s];    // edge ep, node slots 16..31
    const unsigned short* xg = xb + (size_t)g * N_NODES * SCH;
    float a[8] = {0.f, 0.f, 0.f, 0.f, 0.f, 0.f, 0.f, 0.f};
#pragma unroll
    for (int r = 0; r < 8; ++r) {
        int e = __shfl((r < 4) ? mA : mB, (lane & 48) + ((r * 4 + k) & 15), 64);
        uint4 d = *reinterpret_cast<const uint4*>(xg + (size_t)e * SCH + q * 8);
        a[0] += bflo(d.x); a[1] += bfhi(d.x);
        a[2] += bflo(d.y); a[3] += bfhi(d.y);
        a[4] += bflo(d.z); a[5] += bfhi(d.z);
        a[6] += bflo(d.w); a[7] += bfhi(d.w);
    }
#pragma unroll
    for (int j = 0; j < 8; ++j) a[j] += __shfl_xor(a[j], 4, 64);
#pragma unroll
    for (int j = 0; j < 8; ++j) a[j] += __shfl_xor(a[j], 8, 64);
    if ((lane & 12) == 0) {           // k==0 lanes: (ep, q)
        uint4 u;
        u.x = pk2(a[0], a[1]);
        u.y = pk2(a[2], a[3]);
        u.z = pk2(a[4], a[5]);
        u.w = pk2(a[6], a[7]);
        *reinterpret_cast<uint4*>(es + (size_t)(ebase + ep) * CH + g * SCH + q * 8) = u;
    }
}

// Y = es(bf16) @ W(bf16) via mfma_f32_16x16x32_bf16; yb stored SLICED [8][E][32]
__global__ __launch_bounds__(256) void gemm_kernel(const unsigned short* __restrict__ es,
                                                   const unsigned short* __restrict__ wt,
                                                   unsigned short* __restrict__ yb) {
    int wid  = threadIdx.x >> 6;
    int lane = threadIdx.x & 63;
    int m0   = blockIdx.x * 64 + wid * 16;
    if (m0 >= N_EDGES) return;
    int lr = lane & 15;
    int lg = lane >> 4;

    f32x4 acc[16] = {};
    const unsigned short* arow = es + (size_t)(m0 + lr) * CH + lg * 8;
#pragma unroll
    for (int kk = 0; kk < CH; kk += 32) {
        bf16x8 a = *reinterpret_cast<const bf16x8*>(arow + kk);
#pragma unroll
        for (int nt = 0; nt < 16; ++nt) {
            bf16x8 bb = *reinterpret_cast<const bf16x8*>(
                wt + (size_t)(nt * 16 + lr) * CH + kk + lg * 8);
            acc[nt] = __builtin_amdgcn_mfma_f32_16x16x32_bf16(a, bb, acc[nt], 0, 0, 0);
        }
    }
    // D layout: col = lane&15, row = (lane>>4)*4 + r  -> sliced write
#pragma unroll
    for (int nt = 0; nt < 16; ++nt) {
#pragma unroll
        for (int r = 0; r < 4; ++r) {
            int row = m0 + lg * 4 + r;
            yb[((size_t)(nt >> 1) * N_EDGES + row) * SCH + (nt & 1) * 16 + lr] =
                f2bf(acc[nt][r]);
        }
    }
}

// out[n][g*32..] = relu( sum_j yb[g][ell[n][j]][:] )  -- sliced, XCD-pinned.
// Wave = 4 nodes x slice: lanes (np=l>>4, k=(l>>2)&3, q=l&3); per node the 64
// ELL slots live in 4 regs (m0..m3) selected at compile time per quarter.
#define AP_NPB    16                               // nodes per block (4 waves x 4)
#define AP_BLOCKS ((N_NODES / AP_NPB) * NSLICE)    // 3125*8 = 25000
__global__ __launch_bounds__(256) void apply_kernel(
        const unsigned short* __restrict__ yb, const int* __restrict__ deg,
        const unsigned short* __restrict__ ell, float* __restrict__ out) {
    int b = blockIdx.x;
    int g = b & 7;                    // slice == XCD
    int w = threadIdx.x >> 6, lane = threadIdx.x & 63;
    int np = lane >> 4, s = lane & 15, k = (lane >> 2) & 3, q = lane & 3;
    int node = (b >> 3) * AP_NPB + w * 4 + np;     // exact cover: 3125*16 = 50000
    int d = deg[node];
    if (d > ELL_CAP) d = ELL_CAP;
    const unsigned short* er = ell + (size_t)node * ELL_CAP;
    int m0 = er[s], m1 = er[16 + s], m2 = er[32 + s], m3 = er[48 + s];
    int dmax = d;
    dmax = max(dmax, __shfl_xor(dmax, 16, 64));
    dmax = max(dmax, __shfl_xor(dmax, 32, 64));    // wave-uniform max degree
    const unsigned short* yg = yb + (size_t)g * N_EDGES * SCH;
    float a[8] = {0.f, 0.f, 0.f, 0.f, 0.f, 0.f, 0.f, 0.f};
#pragma unroll
    for (int rq = 0; rq < 4; ++rq) {
        if (rq * 16 >= dmax) break;                // uniform branch
        int m = (rq == 0) ? m0 : (rq == 1) ? m1 : (rq == 2) ? m2 : m3;
#pragma unroll
        for (int rr = 0; rr < 4; ++rr) {
            int slot = rq * 16 + rr * 4 + k;
            int e = __shfl(m, (lane & 48) + rr * 4 + k, 64);
            if (slot < d) {
                uint4 dd = *reinterpret_cast<const uint4*>(yg + (size_t)e * SCH + q * 8);
                a[0] += bflo(dd.x); a[1] += bfhi(dd.x);
                a[2] += bflo(dd.y); a[3] += bfhi(dd.y);
                a[4] += bflo(dd.z); a[5] += bfhi(dd.z);
                a[6] += bflo(dd.w); a[7] += bfhi(dd.w);
            }
        }
    }
#pragma unroll
    for (int j = 0; j < 8; ++j) a[j] += __shfl_xor(a[j], 4, 64);
#pragma unroll
    for (int j = 0; j < 8; ++j) a[j] += __shfl_xor(a[j], 8, 64);
    if ((lane & 12) == 0) {           // k==0 lanes: (np, q)
        f32x4 r0, r1;
        r0.x = fmaxf(a[0], 0.f); r0.y = fmaxf(a[1], 0.f);
        r0.z = fmaxf(a[2], 0.f); r0.w = fmaxf(a[3], 0.f);
        r1.x = fmaxf(a[4], 0.f); r1.y = fmaxf(a[5], 0.f);
        r1.z = fmaxf(a[6], 0.f); r1.w = fmaxf(a[7], 0.f);
        float* dst = out + (size_t)node * CH + g * SCH + q * 8;
        *reinterpret_cast<f32x4*>(dst)     = r0;
        *reinterpret_cast<f32x4*>(dst + 4) = r1;
    }
}

extern "C" void kernel_launch(void* const* d_in, const int* in_sizes, int n_in,
                              void* d_out, int out_size, void* d_ws, size_t ws_size,
                              hipStream_t stream) {
    const float* x  = (const float*)d_in[0];
    const int*   he = (const int*)d_in[1];
    const float* w  = (const float*)d_in[2];
    float* out = (float*)d_out;

    // workspace layout
    char* ws = (char*)d_ws;
    unsigned short* wt  = (unsigned short*)ws;                        // 131072 B
    unsigned short* es  = (unsigned short*)(ws + 131072);             // 10240000 B
    unsigned short* yb  = (unsigned short*)(ws + 131072 + 10240000);  // 10240000 B
    int* deg = (int*)(ws + 131072 + 10240000 + 10240000);             // 200000 B
    unsigned short* ell = (unsigned short*)(ws + 131072 + 10240000 + 10240000 + 200000); // 6400000 B

    // xb (bf16 x, sliced [8][N][32], 25.6 MB) lives inside d_out (51.2 MB f32):
    // d_out is only written by the final apply_kernel, lifetimes disjoint.
    unsigned short* xb = (unsigned short*)d_out;

    prep_kernel<<<CONV_BLOCKS + CH + ZERO_BLOCKS, 256, 0, stream>>>(x, xb, w, wt, deg);

    gather_fill_kernel<<<FILL_BLOCKS + GATHER_BLOCKS, 256, 0, stream>>>(xb, he, es, deg, ell);

    {
        int blocks = (N_EDGES + 63) / 64;
        gemm_kernel<<<blocks, 256, 0, stream>>>(es, wt, yb);
    }

    apply_kernel<<<AP_BLOCKS, 256, 0, stream>>>(yb, deg, ell, out);
}

// Round 11
// 141.225 us; speedup vs baseline: 1.3050x; 1.0293x over previous
//
#include <hip/hip_runtime.h>
#include <hip/hip_bf16.h>
#include <hip/hip_fp16.h>

#define N_NODES 50000
#define N_EDGES 20000
#define EDGE_K  32
#define CH      256
#define N_INC   (N_EDGES * EDGE_K)   // 640000 incidences
#define ELL_CAP 64                   // max node degree capacity (Poisson(12.8))
#define NSLICE  8                    // channel slices == XCD count
#define SCH     32                   // channels per slice (32 x 2B = 64B rows)
#define ZROW    N_EDGES              // dedicated all-zeros yb row (ell default)

typedef __attribute__((ext_vector_type(4))) float f32x4;
typedef __attribute__((ext_vector_type(8))) _Float16 f16x8;

static __device__ __forceinline__ __half2 u2h2(unsigned int u) {
    __half2 h; __builtin_memcpy(&h, &u, 4); return h;
}
static __device__ __forceinline__ unsigned int h22u(__half2 h) {
    unsigned int u; __builtin_memcpy(&u, &h, 4); return u;
}
static __device__ __forceinline__ unsigned int pk2h(float a, float b) {
    return h22u(__halves2half2(__float2half_rn(a), __float2half_rn(b)));
}

// Fused prep: x->fp16 sliced [8][N][32] | W^T fp16 | zero deg | ell := ZROW | yb zero-rows
#define CONV_BLOCKS (N_NODES * CH / 8 / 256)           // 6250
#define ZERO_BLOCKS ((N_NODES + 255) / 256)            // 196
#define ELLI_BLOCKS (N_NODES * ELL_CAP / 2 / 256)      // 6250 (uint writes)
__global__ void prep_kernel(const float* __restrict__ x, unsigned short* __restrict__ xb,
                            const float* __restrict__ w, unsigned short* __restrict__ wt,
                            int* __restrict__ deg, unsigned int* __restrict__ ellu,
                            unsigned short* __restrict__ yb) {
    int b = blockIdx.x;
    if (b < CONV_BLOCKS) {
        int i = b * 256 + threadIdx.x;        // one per 8 channels
        int n = i >> 5, sub = i & 31;
        int g = sub >> 2, cp = (sub & 3) * 8;
        const float* src = x + (size_t)n * CH + sub * 8;
        f32x4 v0 = *reinterpret_cast<const f32x4*>(src);
        f32x4 v1 = *reinterpret_cast<const f32x4*>(src + 4);
        uint4 u;
        u.x = pk2h(v0.x, v0.y);
        u.y = pk2h(v0.z, v0.w);
        u.z = pk2h(v1.x, v1.y);
        u.w = pk2h(v1.z, v1.w);
        *reinterpret_cast<uint4*>(xb + ((size_t)g * N_NODES + n) * SCH + cp) = u;
    } else if (b < CONV_BLOCKS + CH) {
        int n = b - CONV_BLOCKS;
        int k = threadIdx.x;
        __half h = __float2half_rn(w[k * CH + n]);
        wt[n * CH + k] = *reinterpret_cast<unsigned short*>(&h);
    } else if (b < CONV_BLOCKS + CH + ZERO_BLOCKS) {
        int i = (b - CONV_BLOCKS - CH) * 256 + threadIdx.x;
        if (i < N_NODES) deg[i] = 0;
    } else if (b < CONV_BLOCKS + CH + ZERO_BLOCKS + ELLI_BLOCKS) {
        int i = (b - CONV_BLOCKS - CH - ZERO_BLOCKS) * 256 + threadIdx.x;
        ellu[i] = 0x4E204E20u;   // two ushorts of 20000 == ZROW
    } else {
        // zero the dedicated yb zero-row for each slice (8 x 32 halves = 256)
        int g = threadIdx.x >> 5, c = threadIdx.x & 31;
        yb[((size_t)g * (N_EDGES + 1) + ZROW) * SCH + c] = 0;
    }
}

// Fused: ELL-fill (head, XCD-partitioned by node range) + sliced gather (tail).
// Gather wave = 4 edges x slice g=blockIdx%8 (pinned to XCD g; 3.2MB slice is
// L2-resident). Lanes (ep=l>>4, k=(l>>2)&3, q=l&3); 8 batched 16B loads,
// packed-fp16 accumulate, shfl_xor reduce over k.
#define FILL_GROUPS   8
#define NODES_PER_GRP (N_NODES / FILL_GROUPS)
#define FILL_WIN      2560
#define FILL_BLOCKS   ((N_INC / FILL_WIN) * FILL_GROUPS) // 2000
#define GGRP          (N_EDGES / 16)                     // 1250
#define GATHER_BLOCKS (GGRP * NSLICE)                    // 10000
__global__ __launch_bounds__(256, 4) void gather_fill_kernel(
        const unsigned short* __restrict__ xb, const int* __restrict__ he,
        unsigned short* __restrict__ es, int* __restrict__ deg,
        unsigned short* __restrict__ ell) {
    int b = blockIdx.x;
    if (b < FILL_BLOCKS) {
        int g  = b % FILL_GROUPS;
        int wn = b / FILL_GROUPS;
        int lo = g * NODES_PER_GRP, hi = lo + NODES_PER_GRP;
        int base = wn * FILL_WIN;
#pragma unroll
        for (int it = 0; it < FILL_WIN / 256; ++it) {
            int i = base + it * 256 + threadIdx.x;
            int node = he[i];
            if (node >= lo && node < hi) {
                int slot = atomicAdd(&deg[node], 1);
                if (slot < ELL_CAP)
                    ell[(size_t)node * ELL_CAP + slot] = (unsigned short)(i >> 5);
            }
        }
        return;
    }
    int gb  = b - FILL_BLOCKS;
    int g   = gb & 7;                 // slice == XCD (round-robin heuristic)
    int grp = gb >> 3;
    int w = threadIdx.x >> 6, lane = threadIdx.x & 63;
    int ebase = grp * 16 + w * 4;     // this wave's 4 edges
    const int* hp = he + (size_t)ebase * EDGE_K;
    int s = lane & 15;
    int ep = lane >> 4, k = (lane >> 2) & 3, q = lane & 3;
    int mA = hp[ep * 32 + s];         // edge ep, node slots 0..15
    int mB = hp[ep * 32 + 16 + s];    // edge ep, node slots 16..31
    const unsigned short* xg = xb + (size_t)g * N_NODES * SCH;
    int hb = lane & 48;
    // all 8 shuffles, then all 8 loads (batched for MLP), then packed adds
    int e0 = __shfl(mA, hb + ((0 + k) & 15), 64);
    int e1 = __shfl(mA, hb + ((4 + k) & 15), 64);
    int e2 = __shfl(mA, hb + ((8 + k) & 15), 64);
    int e3 = __shfl(mA, hb + ((12 + k) & 15), 64);
    int e4 = __shfl(mB, hb + ((0 + k) & 15), 64);
    int e5 = __shfl(mB, hb + ((4 + k) & 15), 64);
    int e6 = __shfl(mB, hb + ((8 + k) & 15), 64);
    int e7 = __shfl(mB, hb + ((12 + k) & 15), 64);
    uint4 d0 = *reinterpret_cast<const uint4*>(xg + (size_t)e0 * SCH + q * 8);
    uint4 d1 = *reinterpret_cast<const uint4*>(xg + (size_t)e1 * SCH + q * 8);
    uint4 d2 = *reinterpret_cast<const uint4*>(xg + (size_t)e2 * SCH + q * 8);
    uint4 d3 = *reinterpret_cast<const uint4*>(xg + (size_t)e3 * SCH + q * 8);
    uint4 d4 = *reinterpret_cast<const uint4*>(xg + (size_t)e4 * SCH + q * 8);
    uint4 d5 = *reinterpret_cast<const uint4*>(xg + (size_t)e5 * SCH + q * 8);
    uint4 d6 = *reinterpret_cast<const uint4*>(xg + (size_t)e6 * SCH + q * 8);
    uint4 d7 = *reinterpret_cast<const uint4*>(xg + (size_t)e7 * SCH + q * 8);
    __half2 a0 = u2h2(0u), a1 = u2h2(0u), a2 = u2h2(0u), a3 = u2h2(0u);
    a0 = __hadd2(a0, u2h2(d0.x)); a1 = __hadd2(a1, u2h2(d0.y));
    a2 = __hadd2(a2, u2h2(d0.z)); a3 = __hadd2(a3, u2h2(d0.w));
    a0 = __hadd2(a0, u2h2(d1.x)); a1 = __hadd2(a1, u2h2(d1.y));
    a2 = __hadd2(a2, u2h2(d1.z)); a3 = __hadd2(a3, u2h2(d1.w));
    a0 = __hadd2(a0, u2h2(d2.x)); a1 = __hadd2(a1, u2h2(d2.y));
    a2 = __hadd2(a2, u2h2(d2.z)); a3 = __hadd2(a3, u2h2(d2.w));
    a0 = __hadd2(a0, u2h2(d3.x)); a1 = __hadd2(a1, u2h2(d3.y));
    a2 = __hadd2(a2, u2h2(d3.z)); a3 = __hadd2(a3, u2h2(d3.w));
    a0 = __hadd2(a0, u2h2(d4.x)); a1 = __hadd2(a1, u2h2(d4.y));
    a2 = __hadd2(a2, u2h2(d4.z)); a3 = __hadd2(a3, u2h2(d4.w));
    a0 = __hadd2(a0, u2h2(d5.x)); a1 = __hadd2(a1, u2h2(d5.y));
    a2 = __hadd2(a2, u2h2(d5.z)); a3 = __hadd2(a3, u2h2(d5.w));
    a0 = __hadd2(a0, u2h2(d6.x)); a1 = __hadd2(a1, u2h2(d6.y));
    a2 = __hadd2(a2, u2h2(d6.z)); a3 = __hadd2(a3, u2h2(d6.w));
    a0 = __hadd2(a0, u2h2(d7.x)); a1 = __hadd2(a1, u2h2(d7.y));
    a2 = __hadd2(a2, u2h2(d7.z)); a3 = __hadd2(a3, u2h2(d7.w));
    // reduce over k (4 lanes)
    a0 = __hadd2(a0, u2h2(__shfl_xor(h22u(a0), 4, 64)));
    a1 = __hadd2(a1, u2h2(__shfl_xor(h22u(a1), 4, 64)));
    a2 = __hadd2(a2, u2h2(__shfl_xor(h22u(a2), 4, 64)));
    a3 = __hadd2(a3, u2h2(__shfl_xor(h22u(a3), 4, 64)));
    a0 = __hadd2(a0, u2h2(__shfl_xor(h22u(a0), 8, 64)));
    a1 = __hadd2(a1, u2h2(__shfl_xor(h22u(a1), 8, 64)));
    a2 = __hadd2(a2, u2h2(__shfl_xor(h22u(a2), 8, 64)));
    a3 = __hadd2(a3, u2h2(__shfl_xor(h22u(a3), 8, 64)));
    if ((lane & 12) == 0) {           // k==0 lanes: (ep, q)
        uint4 u;
        u.x = h22u(a0); u.y = h22u(a1); u.z = h22u(a2); u.w = h22u(a3);
        *reinterpret_cast<uint4*>(es + (size_t)(ebase + ep) * CH + g * SCH + q * 8) = u;
    }
}

// Y = es(fp16) @ W(fp16) via mfma_f32_16x16x32_f16; yb stored SLICED [8][E+1][32]
__global__ __launch_bounds__(256) void gemm_kernel(const unsigned short* __restrict__ es,
                                                   const unsigned short* __restrict__ wt,
                                                   unsigned short* __restrict__ yb) {
    int wid  = threadIdx.x >> 6;
    int lane = threadIdx.x & 63;
    int m0   = blockIdx.x * 64 + wid * 16;
    if (m0 >= N_EDGES) return;
    int lr = lane & 15;
    int lg = lane >> 4;

    f32x4 acc[16] = {};
    const unsigned short* arow = es + (size_t)(m0 + lr) * CH + lg * 8;
#pragma unroll
    for (int kk = 0; kk < CH; kk += 32) {
        f16x8 a = *reinterpret_cast<const f16x8*>(arow + kk);
#pragma unroll
        for (int nt = 0; nt < 16; ++nt) {
            f16x8 bb = *reinterpret_cast<const f16x8*>(
                wt + (size_t)(nt * 16 + lr) * CH + kk + lg * 8);
            acc[nt] = __builtin_amdgcn_mfma_f32_16x16x32_f16(a, bb, acc[nt], 0, 0, 0);
        }
    }
    // D layout: col = lane&15, row = (lane>>4)*4 + r  -> sliced write
#pragma unroll
    for (int nt = 0; nt < 16; ++nt) {
#pragma unroll
        for (int r = 0; r < 4; ++r) {
            int row = m0 + lg * 4 + r;
            __half h = __float2half_rn(acc[nt][r]);
            yb[((size_t)(nt >> 1) * (N_EDGES + 1) + row) * SCH + (nt & 1) * 16 + lr] =
                *reinterpret_cast<unsigned short*>(&h);
        }
    }
}

// out[n][g*32..] = relu( sum_j yb[g][ell[n][j]][:] ) -- sliced, XCD-pinned,
// zero-row-padded ELL -> unconditional batched loads, packed-fp16 accumulate.
#define AP_NPB    16                               // nodes per block (4 waves x 4)
#define AP_BLOCKS ((N_NODES / AP_NPB) * NSLICE)    // 25000
__global__ __launch_bounds__(256) void apply_kernel(
        const unsigned short* __restrict__ yb, const int* __restrict__ deg,
        const unsigned short* __restrict__ ell, float* __restrict__ out) {
    int b = blockIdx.x;
    int g = b & 7;                    // slice == XCD
    int w = threadIdx.x >> 6, lane = threadIdx.x & 63;
    int np = lane >> 4, s = lane & 15, k = (lane >> 2) & 3, q = lane & 3;
    int node = (b >> 3) * AP_NPB + w * 4 + np;     // exact cover
    int d = deg[node];
    if (d > ELL_CAP) d = ELL_CAP;
    const unsigned short* er = ell + (size_t)node * ELL_CAP;
    int m0 = er[s], m1 = er[16 + s], m2 = er[32 + s], m3 = er[48 + s];
    int dmax = d;
    dmax = max(dmax, __shfl_xor(dmax, 16, 64));
    dmax = max(dmax, __shfl_xor(dmax, 32, 64));    // wave-uniform max degree
    const unsigned short* yg = yb + (size_t)g * (N_EDGES + 1) * SCH;
    int hb = lane & 48;
    __half2 a0 = u2h2(0u), a1 = u2h2(0u), a2 = u2h2(0u), a3 = u2h2(0u);
    for (int rq = 0; rq < 4; ++rq) {
        if (rq * 16 >= dmax) break;                // uniform branch
        int m = (rq == 0) ? m0 : (rq == 1) ? m1 : (rq == 2) ? m2 : m3;
        int e0 = __shfl(m, hb + 0 + k, 64);
        int e1 = __shfl(m, hb + 4 + k, 64);
        int e2 = __shfl(m, hb + 8 + k, 64);
        int e3 = __shfl(m, hb + 12 + k, 64);
        uint4 d0 = *reinterpret_cast<const uint4*>(yg + (size_t)e0 * SCH + q * 8);
        uint4 d1 = *reinterpret_cast<const uint4*>(yg + (size_t)e1 * SCH + q * 8);
        uint4 d2 = *reinterpret_cast<const uint4*>(yg + (size_t)e2 * SCH + q * 8);
        uint4 d3 = *reinterpret_cast<const uint4*>(yg + (size_t)e3 * SCH + q * 8);
        a0 = __hadd2(a0, u2h2(d0.x)); a1 = __hadd2(a1, u2h2(d0.y));
        a2 = __hadd2(a2, u2h2(d0.z)); a3 = __hadd2(a3, u2h2(d0.w));
        a0 = __hadd2(a0, u2h2(d1.x)); a1 = __hadd2(a1, u2h2(d1.y));
        a2 = __hadd2(a2, u2h2(d1.z)); a3 = __hadd2(a3, u2h2(d1.w));
        a0 = __hadd2(a0, u2h2(d2.x)); a1 = __hadd2(a1, u2h2(d2.y));
        a2 = __hadd2(a2, u2h2(d2.z)); a3 = __hadd2(a3, u2h2(d2.w));
        a0 = __hadd2(a0, u2h2(d3.x)); a1 = __hadd2(a1, u2h2(d3.y));
        a2 = __hadd2(a2, u2h2(d3.z)); a3 = __hadd2(a3, u2h2(d3.w));
    }
    // reduce over k (4 lanes)
    a0 = __hadd2(a0, u2h2(__shfl_xor(h22u(a0), 4, 64)));
    a1 = __hadd2(a1, u2h2(__shfl_xor(h22u(a1), 4, 64)));
    a2 = __hadd2(a2, u2h2(__shfl_xor(h22u(a2), 4, 64)));
    a3 = __hadd2(a3, u2h2(__shfl_xor(h22u(a3), 4, 64)));
    a0 = __hadd2(a0, u2h2(__shfl_xor(h22u(a0), 8, 64)));
    a1 = __hadd2(a1, u2h2(__shfl_xor(h22u(a1), 8, 64)));
    a2 = __hadd2(a2, u2h2(__shfl_xor(h22u(a2), 8, 64)));
    a3 = __hadd2(a3, u2h2(__shfl_xor(h22u(a3), 8, 64)));
    if ((lane & 12) == 0) {           // k==0 lanes: (np, q)
        float2 f0 = __half22float2(a0);
        float2 f1 = __half22float2(a1);
        float2 f2 = __half22float2(a2);
        float2 f3 = __half22float2(a3);
        f32x4 r0, r1;
        r0.x = fmaxf(f0.x, 0.f); r0.y = fmaxf(f0.y, 0.f);
        r0.z = fmaxf(f1.x, 0.f); r0.w = fmaxf(f1.y, 0.f);
        r1.x = fmaxf(f2.x, 0.f); r1.y = fmaxf(f2.y, 0.f);
        r1.z = fmaxf(f3.x, 0.f); r1.w = fmaxf(f3.y, 0.f);
        float* dst = out + (size_t)node * CH + g * SCH + q * 8;
        *reinterpret_cast<f32x4*>(dst)     = r0;
        *reinterpret_cast<f32x4*>(dst + 4) = r1;
    }
}

extern "C" void kernel_launch(void* const* d_in, const int* in_sizes, int n_in,
                              void* d_out, int out_size, void* d_ws, size_t ws_size,
                              hipStream_t stream) {
    const float* x  = (const float*)d_in[0];
    const int*   he = (const int*)d_in[1];
    const float* w  = (const float*)d_in[2];
    float* out = (float*)d_out;

    // workspace layout
    char* ws = (char*)d_ws;
    unsigned short* wt  = (unsigned short*)ws;                        // 131072 B
    unsigned short* es  = (unsigned short*)(ws + 131072);             // 10240000 B
    unsigned short* yb  = (unsigned short*)(ws + 10371072);           // 8*(20001)*32*2 = 10240512 B
    int* deg = (int*)(ws + 20611584);                                 // 200000 B
    unsigned short* ell = (unsigned short*)(ws + 20811584);           // 6400000 B

    // xb (fp16 x, sliced [8][N][32], 25.6 MB) lives inside d_out (51.2 MB f32)
    unsigned short* xb = (unsigned short*)d_out;

    prep_kernel<<<CONV_BLOCKS + CH + ZERO_BLOCKS + ELLI_BLOCKS + 1, 256, 0, stream>>>(
        x, xb, w, wt, deg, (unsigned int*)ell, yb);

    gather_fill_kernel<<<FILL_BLOCKS + GATHER_BLOCKS, 256, 0, stream>>>(xb, he, es, deg, ell);

    {
        int blocks = (N_EDGES + 63) / 64;
        gemm_kernel<<<blocks, 256, 0, stream>>>(es, wt, yb);
    }

    apply_kernel<<<AP_BLOCKS, 256, 0, stream>>>(yb, deg, ell, out);
}